// Round 12
// baseline (121.138 us; speedup 1.0000x reference)
//
#include <hip/hip_runtime.h>
#include <math.h>

#define DEVI __device__ __forceinline__

static constexpr float KD[10] = {
  0.027333068345077982f,  0.029519490925774643f, -0.039134249302383094f,
  0.1993975339773936f,    0.7234076904024206f,    0.6339789634582119f,
  0.01660210576452232f,  -0.17532808990845047f,  -0.021101834024758855f,
  0.019538882735286728f};

// ---------- workspace layout (float offsets) ----------
#define CE_OFF     0         // 105000 floats (ce per pixel, 0 for non-negatives)
#define PH_OFF     105056    // exp-hist partials: NBs x 256 uints per scale (16B-aligned)
#define PH1_REL    80128     // NB3*256
#define PH2_REL    100352    // + NB4*256
#define MH_OFF     210528    // m8-hist partials: 3 x 96 x 256 uints
#define SLOTGT_OFF 284256    // 3 x 96 floats (per-block sum of exp>ibin)
#define SLOT2_OFF  284544    // 3 x 96 floats (per-block sum of exp==ibin & m8>jbin)
#define BAR_OFF    284832    // 2 uints: barrier counter + generation
#define CBUF_OFF   284840    // 3 x CAPC floats
#define CAPC       81920
#define PART_OFF   530600    // 3 x PART_STRIDE floats (per-block partials)
#define PART_STRIDE 7680     // >= 4*NB3*6

#define NB3 313
#define NB4 79
#define NB5 20
#define NBR 96               // tail blocks per scale
#define NBLK (NBR * 3)       // total tail blocks (must be co-resident: 288 << 512 cap)

DEVI float wave_sum(float v) {
#pragma unroll
  for (int d = 32; d; d >>= 1) v += __shfl_down(v, d);
  return v;
}

DEVI float block_sum(float v, float* sh) {
  int lane = threadIdx.x & 63, wid = threadIdx.x >> 6;
  v = wave_sum(v);
  if (lane == 0) sh[wid] = v;
  __syncthreads();
  if (threadIdx.x == 0) {
    float s = 0.f;
    int nw = blockDim.x >> 6;
    for (int w = 0; w < nw; ++w) s += sh[w];
    sh[0] = s;
  }
  __syncthreads();
  float r = sh[0];
  __syncthreads();
  return r;
}

// inclusive suffix sum across 256 threads; sh must be int[256]
DEVI int suffix_scan_256(int v, int* sh) {
  int t = threadIdx.x;
  sh[t] = v;
  __syncthreads();
#pragma unroll
  for (int off = 1; off < 256; off <<= 1) {
    int x = (t + off < 256) ? sh[t + off] : 0;
    __syncthreads();
    sh[t] += x;
    __syncthreads();
  }
  return sh[t];
}

// generation-based grid barrier (device-scope atomics; all NBLK blocks co-resident)
DEVI void grid_barrier(unsigned* bar) {
  __syncthreads();
  if (threadIdx.x == 0) {
    __threadfence();
    unsigned g = atomicAdd(&bar[1], 0u);                 // snapshot generation
    unsigned arrived = atomicAdd(&bar[0], 1u) + 1u;
    if (arrived == (unsigned)NBLK) {
      atomicExch(&bar[0], 0u);
      __threadfence();
      atomicAdd(&bar[1], 1u);                            // release
    } else {
      while (atomicAdd(&bar[1], 0u) == g) __builtin_amdgcn_s_sleep(2);
    }
    __threadfence();
  }
  __syncthreads();
}

// HALF of waverec3+smooth_l1: outputs [50h, 50h+50). Dependency cone:
//  H=0: a2[0..28] <- a1[0..18] <- c[0..13]
//  H=1: a2[25..53] <- a1[12..30] <- c[6..19]
template <int H>
DEVI float recon_sl1_half(const float* __restrict__ rb, const float* __restrict__ gb,
                          int rc0, int gc0, size_t HW, float off) {
  constexpr int CLO  = (H == 0) ? 0 : 6;
  constexpr int A1LO = (H == 0) ? 0 : 12;
  constexpr int J2LO = (H == 0) ? 0 : 25;

  float c[14];
#pragma unroll
  for (int i = 0; i < 14; ++i)
    c[i] = rb[(size_t)(rc0 + CLO + i) * HW] - gb[(size_t)(gc0 + CLO + i) * HW];

  float a1[19];
#pragma unroll
  for (int k = 0; k < 19; ++k) {
    int o1 = A1LO + k;
    int b = (o1 >> 1) - CLO;
    if (o1 & 1)
      a1[k] = KD[0]*c[b] + KD[2]*c[b+1] + KD[4]*c[b+2] + KD[6]*c[b+3] + KD[8]*c[b+4];
    else
      a1[k] = KD[1]*c[b] + KD[3]*c[b+1] + KD[5]*c[b+2] + KD[7]*c[b+3] + KD[9]*c[b+4];
  }

  float w0 = 0.f, w1 = 0.f, w2 = 0.f, w3 = 0.f, w4 = 0.f;
  float acc = 0.f;
#pragma unroll
  for (int k = 0; k < 29; ++k) {
    int j2 = J2LO + k;
    int b = (j2 >> 1) - A1LO;
    float a2v;
    if (j2 & 1)
      a2v = KD[0]*a1[b] + KD[2]*a1[b+1] + KD[4]*a1[b+2] + KD[6]*a1[b+3] + KD[8]*a1[b+4];
    else
      a2v = KD[1]*a1[b] + KD[3]*a1[b+1] + KD[5]*a1[b+2] + KD[7]*a1[b+3] + KD[9]*a1[b+4];
    w0 = w1; w1 = w2; w2 = w3; w3 = w4; w4 = a2v;
    if (k >= 4) {
      float ve = KD[1]*w0 + KD[3]*w1 + KD[5]*w2 + KD[7]*w3 + KD[9]*w4 + off;
      float vo = KD[0]*w0 + KD[2]*w1 + KD[4]*w2 + KD[6]*w3 + KD[8]*w4 + off;
      float ae = fabsf(ve);
      acc += (ae < 1.f) ? 0.5f * ve * ve : ae - 0.5f;
      float ao = fabsf(vo);
      acc += (ao < 1.f) ? 0.5f * vo * vo : ao - 0.5f;
    }
  }
  return acc;
}

// Fused over 3 scales; blockIdx.y in [0,4): axis = y>>1, half = y&1.
// CE/mask/hist work only in y==0 blocks. Block (0,0) also zeroes out + barrier.
__global__ void __launch_bounds__(256, 2)
pixel_kernel(const float* __restrict__ cls3, const float* __restrict__ reg3, const float* __restrict__ gt3,
             const float* __restrict__ cls4, const float* __restrict__ reg4, const float* __restrict__ gt4,
             const float* __restrict__ cls5, const float* __restrict__ reg5, const float* __restrict__ gt5,
             float* __restrict__ ws, float* __restrict__ out) {
  int bx = blockIdx.x, y = blockIdx.y;
  int axis = y >> 1, half = y & 1;
  const float *cls, *reg, *gt;
  int M, HW, ceOff, partBase, phRel, nb, lbx;
  if (bx < NB3) {
    cls = cls3; reg = reg3; gt = gt3; M = 80000; HW = 10000;
    ceOff = 0; partBase = PART_OFF; phRel = 0; nb = NB3; lbx = bx;
  } else if (bx < NB3 + NB4) {
    cls = cls4; reg = reg4; gt = gt4; M = 20000; HW = 2500;
    ceOff = 80000; partBase = PART_OFF + PART_STRIDE; phRel = PH1_REL; nb = NB4; lbx = bx - NB3;
  } else {
    cls = cls5; reg = reg5; gt = gt5; M = 5000; HW = 625;
    ceOff = 100000; partBase = PART_OFF + 2 * PART_STRIDE; phRel = PH2_REL; nb = NB5; lbx = bx - NB3 - NB4;
  }
  float* ceArr = ws + ceOff;
  unsigned* ph = (unsigned*)(ws + PH_OFF) + phRel;

  if (bx == 0 && y == 0) {
    if (threadIdx.x < 3) out[threadIdx.x] = 0.f;
    if (threadIdx.x == 4) ((unsigned*)(ws + BAR_OFF))[0] = 0u;
    if (threadIdx.x == 5) ((unsigned*)(ws + BAR_OFF))[1] = 0u;
  }

  __shared__ unsigned hlds[256];
  __shared__ float shp[4][6];
  hlds[threadIdx.x] = 0u;
  __syncthreads();

  int p = lbx * 256 + threadIdx.x;
  float cnt_pos = 0.f, cnt_neg = 0.f, s_ce_pos = 0.f, s_tcl_ttm = 0.f, s_tcl_negm = 0.f;
  float s_ttm_pp = 0.f;
  if (p < M) {
    int n = p / HW, hw = p % HW;
    const float* gb = gt  + (size_t)n * 45 * HW + hw;
    const float* rb = reg + (size_t)n * 42 * HW + hw;
    float tr = gb[0], train = gb[2*(size_t)HW];
    float ttm = tr * train;

    if (y == 0) {
      const float* cb = cls + (size_t)n * 4 * HW + hw;
      float l0 = cb[0], l1 = cb[(size_t)HW], l2 = cb[2*(size_t)HW], l3 = cb[3*(size_t)HW];
      float tcl = gb[(size_t)HW];

      float m1 = fmaxf(l0, l1);
      float lse1 = m1 + __logf(__expf(l0 - m1) + __expf(l1 - m1));
      float ce_tr = lse1 - ((tr > 0.5f) ? l1 : l0);
      float m2 = fmaxf(l2, l3);
      float lse2 = m2 + __logf(__expf(l2 - m2) + __expf(l3 - m2));
      float ce_tcl = lse2 - ((tcl > 0.5f) ? l3 : l2);

      bool pos = ttm > 0.f;
      bool neg = ((1.f - tr) * train) > 0.f;
      float cev = neg ? ce_tr : 0.f;
      ceArr[p] = cev;
      if (neg) atomicAdd(&hlds[__float_as_uint(cev) >> 23], 1u);  // LDS-local

      cnt_pos = pos ? 1.f : 0.f;
      cnt_neg = neg ? 1.f : 0.f;
      s_ce_pos = pos ? ce_tr : 0.f;
      s_tcl_ttm = ce_tcl * ttm;
      s_tcl_negm = ce_tcl * (1.f - ttm);
    }

    int rc0 = axis ? 21 : 0;
    int gc0 = axis ? 24 : 3;
    float dc = rb[(size_t)(rc0 + 20) * HW] - gb[(size_t)(gc0 + 20) * HW];
    float pp = half ? recon_sl1_half<1>(rb, gb, rc0, gc0, (size_t)HW, dc)
                    : recon_sl1_half<0>(rb, gb, rc0, gc0, (size_t)HW, dc);
    s_ttm_pp = ttm * pp;
  }

  int lane = threadIdx.x & 63, wid = threadIdx.x >> 6;
  cnt_pos = wave_sum(cnt_pos);
  cnt_neg = wave_sum(cnt_neg);
  s_ce_pos = wave_sum(s_ce_pos);
  s_tcl_ttm = wave_sum(s_tcl_ttm);
  s_tcl_negm = wave_sum(s_tcl_negm);
  s_ttm_pp = wave_sum(s_ttm_pp);
  if (lane == 0) {
    shp[wid][0] = cnt_pos; shp[wid][1] = cnt_neg; shp[wid][2] = s_ce_pos;
    shp[wid][3] = s_tcl_ttm; shp[wid][4] = s_tcl_negm; shp[wid][5] = s_ttm_pp;
  }
  __syncthreads();
  if (threadIdx.x < 6) {
    float s = shp[0][threadIdx.x] + shp[1][threadIdx.x] + shp[2][threadIdx.x] + shp[3][threadIdx.x];
    ws[partBase + (size_t)(y * nb + lbx) * 6 + threadIdx.x] = s;
  }
  if (y == 0)
    ph[(size_t)lbx * 256 + threadIdx.x] = hlds[threadIdx.x];
}

// ONE kernel for the whole OHEM tail. grid = (NBR, 3); 2 grid barriers.
__global__ void fused_tail(float* __restrict__ ws, float* __restrict__ out) {
  const int s = blockIdx.y, r = blockIdx.x, t = threadIdx.x;
  const int M   = (s == 0) ? 80000 : (s == 1 ? 20000 : 5000);
  const int off = (s == 0) ? 0     : (s == 1 ? 80000 : 100000);
  const int nb0 = (s == 0) ? NB3   : (s == 1 ? NB4   : NB5);
  const int phRel = (s == 0) ? 0 : (s == 1 ? PH1_REL : PH2_REL);
  unsigned* bar = (unsigned*)(ws + BAR_OFF);
  const float* ce = ws + off;

  __shared__ int sh[256];
  __shared__ int sel[2];
  __shared__ float red[4];
  __shared__ unsigned hbin[256];
  __shared__ unsigned mhL[256];
  __shared__ float bsL[256];
  __shared__ unsigned wcnt;

  // ---- Phase A: redundant selA (identical result in all blocks of scale s) ----
  const float* part = ws + PART_OFF + s * PART_STRIDE;
  int npart = 4 * nb0;
  float a0 = 0.f, a1 = 0.f, a2 = 0.f, a3 = 0.f, a4 = 0.f, a5 = 0.f;
  for (int i = t; i < npart; i += 256) {
    const float* p6 = part + (size_t)i * 6;
    a0 += p6[0]; a1 += p6[1]; a2 += p6[2]; a3 += p6[3]; a4 += p6[4]; a5 += p6[5];
  }
  a0 = block_sum(a0, red);
  a1 = block_sum(a1, red);
  a2 = block_sum(a2, red);
  a3 = block_sum(a3, red);
  a4 = block_sum(a4, red);
  a5 = block_sum(a5, red);

  float cnt_pos = a0, cnt_negf = a1;
  int cnt_neg = (int)cnt_negf;
  float kf = (cnt_pos > 0.f) ? fminf(cnt_negf, floorf(3.f * cnt_pos)) : 100.f;
  int k_take = min((int)kf, cnt_neg);

  int ibin, rem;
  if (k_take >= cnt_neg) { ibin = -1; rem = 0; }        // take all negatives
  else if (k_take <= 0)  { ibin = 256; rem = 0; }       // take none
  else {
    hbin[t] = 0u;
    __syncthreads();
    const uint4* ph4 = (const uint4*)((const unsigned*)(ws + PH_OFF) + phRel);
    int n4 = nb0 * 64;
    for (int i = t; i < n4; i += 256) {
      uint4 u = ph4[i];
      int b0 = (i * 4) & 255;
      atomicAdd(&hbin[b0 + 0], u.x);
      atomicAdd(&hbin[b0 + 1], u.y);
      atomicAdd(&hbin[b0 + 2], u.z);
      atomicAdd(&hbin[b0 + 3], u.w);
    }
    __syncthreads();
    int h = (int)hbin[t];
    int suf = suffix_scan_256(h, sh);
    int above = suf - h;
    if (suf >= k_take && above < k_take) { sel[0] = t; sel[1] = k_take - above; }
    __syncthreads();
    ibin = sel[0]; rem = sel[1];
    __syncthreads();
  }

  // ---- Phase B: one ce pass: sumGT slot + LDS m8 hist & bin-sums ----
  mhL[t] = 0u; bsL[t] = 0.f;
  __syncthreads();
  float sgt = 0.f;
  for (int i = r * 256 + t; i < M; i += NBR * 256) {
    float v = ce[i];
    unsigned b = __float_as_uint(v);
    int e = (int)(b >> 23);
    if (e > ibin) sgt += v;
    else if (e == ibin && rem > 0) {
      int m8 = (int)((b >> 15) & 255u);
      atomicAdd(&mhL[m8], 1u);
      atomicAdd(&bsL[m8], v);
    }
  }
  sgt = block_sum(sgt, red);           // internal syncs also order LDS atomics
  if (t == 0) ws[SLOTGT_OFF + s * NBR + r] = sgt;
  unsigned* mh = (unsigned*)(ws + MH_OFF) + ((size_t)s * NBR + r) * 256;
  mh[t] = mhL[t];

  grid_barrier(bar);

  // ---- Phase C+D: redundant jbin select; gt2 from LDS bin-sums; rank-write ----
  int jbin = 0, rem2 = 0, jcnt = 0;
  if (rem > 0) {
    hbin[t] = 0u;
    __syncthreads();
    const uint4* mh4 = (const uint4*)((const unsigned*)(ws + MH_OFF) + (size_t)s * NBR * 256);
    for (int i = t; i < NBR * 64; i += 256) {
      uint4 u = mh4[i];
      int b0 = (i * 4) & 255;
      atomicAdd(&hbin[b0 + 0], u.x);
      atomicAdd(&hbin[b0 + 1], u.y);
      atomicAdd(&hbin[b0 + 2], u.z);
      atomicAdd(&hbin[b0 + 3], u.w);
    }
    __syncthreads();
    int h = (int)hbin[t];
    int suf = suffix_scan_256(h, sh);
    int above = suf - h;
    if (suf >= rem && above < rem) { sel[0] = t; sel[1] = rem - above; }
    __syncthreads();
    jbin = sel[0]; rem2 = sel[1];
    __syncthreads();

    // gt2 = sum of this block's values in bins > jbin (from LDS bin-sums)
    float loc = (t > jbin) ? bsL[t] : 0.f;
    float gt2 = block_sum(loc, red);
    if (t == 0) ws[SLOT2_OFF + s * NBR + r] = gt2;

    // prefix of per-block jbin counts -> contention-free write base
    const unsigned* mh_s = (const unsigned*)(ws + MH_OFF) + (size_t)s * NBR * 256;
    int cval = (t < NBR) ? (int)mh_s[(size_t)t * 256 + jbin] : 0;
    sh[t] = cval;
    __syncthreads();
#pragma unroll
    for (int o = 1; o < 128; o <<= 1) {
      int x = (t >= o) ? sh[t - o] : 0;
      __syncthreads();
      sh[t] += x;
      __syncthreads();
    }
    int base = (r > 0) ? sh[r - 1] : 0;
    jcnt = sh[NBR - 1];

    if (t == 0) wcnt = 0u;
    __syncthreads();
    float* cbuf = ws + CBUF_OFF + (size_t)s * CAPC;
    for (int i = r * 256 + t; i < M; i += NBR * 256) {
      float v = ce[i];
      unsigned b = __float_as_uint(v);
      if ((int)(b >> 23) == ibin && (int)((b >> 15) & 255u) == jbin) {
        unsigned idx = (unsigned)base + atomicAdd(&wcnt, 1u);
        if (idx < CAPC) cbuf[idx] = v;
      }
    }
  } else {
    if (t == 0) ws[SLOT2_OFF + s * NBR + r] = 0.f;
  }

  grid_barrier(bar);

  // ---- Phase F: one block per scale assembles the losses ----
  if (r != 0) return;

  float lpart = 0.f;
  if (t < NBR) {
    lpart = ws[SLOTGT_OFF + s * NBR + t];
    if (rem > 0) lpart += ws[SLOT2_OFF + s * NBR + t];
  }
  float loss_neg = block_sum(lpart, red);

  if (rem > 0 && rem2 > 0) {
    int cnt = min(jcnt, CAPC);
    const float* cbuf = ws + CBUF_OFF + (size_t)s * CAPC;
    int* hbinI = (int*)hbin;

    // pass 1: mantissa bits 14..7
    hbinI[t] = 0; __syncthreads();
    for (int i = t; i < cnt; i += 256)
      atomicAdd(&hbinI[(__float_as_uint(cbuf[i]) >> 7) & 255u], 1);
    __syncthreads();
    int h = hbinI[t];
    int suf = suffix_scan_256(h, sh);
    int above = suf - h;
    int remcur = rem2;
    if (suf >= remcur && above < remcur) { sel[0] = t; sel[1] = remcur - above; }
    __syncthreads();
    int b1 = sel[0]; remcur = sel[1];
    __syncthreads();

    // pass 2: mantissa bits 6..0
    hbinI[t] = 0; __syncthreads();
    for (int i = t; i < cnt; i += 256) {
      unsigned b = __float_as_uint(cbuf[i]);
      if (((b >> 7) & 255u) == (unsigned)b1) atomicAdd(&hbinI[b & 127u], 1);
    }
    __syncthreads();
    h = (t < 128) ? hbinI[t] : 0;
    suf = suffix_scan_256(h, sh);
    above = suf - h;
    if (t < 128 && suf >= remcur && above < remcur) { sel[0] = t; }
    __syncthreads();
    int b0 = sel[0];
    __syncthreads();

    unsigned prefix = ((unsigned)ibin << 23) | ((unsigned)jbin << 15) |
                      ((unsigned)b1 << 7) | (unsigned)b0;
    float tval = __uint_as_float(prefix);

    float sum_in = 0.f, cgt = 0.f;
    for (int i = t; i < cnt; i += 256) {
      unsigned b = __float_as_uint(cbuf[i]);
      if (b > prefix) { sum_in += cbuf[i]; cgt += 1.f; }
    }
    sum_in = block_sum(sum_in, red);
    cgt = block_sum(cgt, red);
    loss_neg += sum_in + ((float)rem2 - cgt) * tval;
  }

  if (t == 0) {
    float n_pos = cnt_pos;
    float loss_pos = (n_pos > 0.f) ? a2 : 0.f;
    float loss_tr = (loss_pos + loss_neg) / (n_pos + kf);

    float negm = (float)M - n_pos;
    float mp = a3 / fmaxf(n_pos, 1.f);
    float mn = a4 / fmaxf(negm, 1.f);
    float loss_tcl = (n_pos > 0.f) ? (mp + 0.5f * mn) : 0.f;

    float loss_ct = (n_pos > 0.f) ? (0.5f * a5 / (n_pos * 200.f)) : 0.f;

    atomicAdd(&out[0], loss_tr);
    atomicAdd(&out[1], loss_tcl);
    atomicAdd(&out[2], loss_ct);
  }
}

extern "C" void kernel_launch(void* const* d_in, const int* in_sizes, int n_in,
                              void* d_out, int out_size, void* d_ws, size_t ws_size,
                              hipStream_t stream) {
  (void)in_sizes; (void)n_in; (void)out_size; (void)ws_size;
  const float* cls3 = (const float*)d_in[0];
  const float* reg3 = (const float*)d_in[1];
  const float* gt3  = (const float*)d_in[2];
  const float* cls4 = (const float*)d_in[3];
  const float* reg4 = (const float*)d_in[4];
  const float* gt4  = (const float*)d_in[5];
  const float* cls5 = (const float*)d_in[6];
  const float* reg5 = (const float*)d_in[7];
  const float* gt5  = (const float*)d_in[8];

  float* ws = (float*)d_ws;
  float* out = (float*)d_out;

  pixel_kernel<<<dim3(NB3 + NB4 + NB5, 4), 256, 0, stream>>>(
      cls3, reg3, gt3, cls4, reg4, gt4, cls5, reg5, gt5, ws, out);

  fused_tail<<<dim3(NBR, 3), 256, 0, stream>>>(ws, out);
}